// Round 1
// baseline (7552.455 us; speedup 1.0000x reference)
//
#include <hip/hip_runtime.h>
#include <cstdint>

#define B_  64
#define T_  4096
#define F_  100
#define H_  200
#define G_  600   // 3H

typedef _Float16 half2_t __attribute__((ext_vector_type(2)));

__device__ __forceinline__ float sigmoidf_(float x) {
    return 1.0f / (1.0f + __expf(-x));
}
__device__ __forceinline__ float tanh_fast_(float x) {
    float e = __expf(-2.0f * x);
    return (1.0f - e) / (1.0f + e);
}

__device__ __forceinline__ float fdot2_(half2_t a, half2_t b, float c) {
#if __has_builtin(__builtin_amdgcn_fdot2)
    return __builtin_amdgcn_fdot2(a, b, c, false);
#else
    return fmaf((float)a.x, (float)b.x, fmaf((float)a.y, (float)b.y, c));
#endif
}

// ---------------- Phase 0: pack Wh (f32, row-major [200,600]) -> half2 [100][600] ----------------
// whp[k*600 + c] = (Wh[2k][c], Wh[2k+1][c])
__global__ void prep_whp(const float* __restrict__ Wh, half2_t* __restrict__ whp) {
    int i = blockIdx.x * 256 + threadIdx.x;
    if (i < 100 * G_) {
        int k = i / G_, c = i - k * G_;
        half2_t v;
        v.x = (_Float16)Wh[(2 * k) * G_ + c];
        v.y = (_Float16)Wh[(2 * k + 1) * G_ + c];
        whp[i] = v;
    }
}

// ---------------- Phase 1: gi = x @ Wi + bi (fp32) ----------------
// 320 threads, 2 columns per thread: halves the uniform-broadcast LDS read
// traffic (the per-CU LDS return path, ~128 B/cy, was the limiter at 640 thr).
__global__ __launch_bounds__(320)
void gi_kernel(const float* __restrict__ x, const float* __restrict__ Wi,
               const float* __restrict__ bi, float* __restrict__ gi,
               int t0, int TC) {
    __shared__ float xT[F_ * 68];
    int row0 = blockIdx.x * 64;
    int b    = row0 / TC;
    int tc0  = row0 - b * TC;
    const float* xrow = x + ((size_t)b * T_ + t0 + tc0) * F_;
    for (int i = threadIdx.x; i < 64 * F_; i += 320) {
        int r = i / F_, f = i - r * F_;
        xT[f * 68 + r] = xrow[i];
    }
    __syncthreads();
    int c0 = threadIdx.x < 300 ? (int)threadIdx.x : 299;
    int c1 = c0 + 300;
    float acc0[64], acc1[64];
    #pragma unroll
    for (int r = 0; r < 64; ++r) { acc0[r] = 0.f; acc1[r] = 0.f; }
    for (int f = 0; f < F_; ++f) {
        float w0 = Wi[f * G_ + c0];
        float w1 = Wi[f * G_ + c1];
        const float4* xf = (const float4*)&xT[f * 68];
        #pragma unroll
        for (int q = 0; q < 16; ++q) {
            float4 v = xf[q];
            acc0[4*q+0] = fmaf(v.x, w0, acc0[4*q+0]);
            acc0[4*q+1] = fmaf(v.y, w0, acc0[4*q+1]);
            acc0[4*q+2] = fmaf(v.z, w0, acc0[4*q+2]);
            acc0[4*q+3] = fmaf(v.w, w0, acc0[4*q+3]);
            acc1[4*q+0] = fmaf(v.x, w1, acc1[4*q+0]);
            acc1[4*q+1] = fmaf(v.y, w1, acc1[4*q+1]);
            acc1[4*q+2] = fmaf(v.z, w1, acc1[4*q+2]);
            acc1[4*q+3] = fmaf(v.w, w1, acc1[4*q+3]);
        }
    }
    if (threadIdx.x < 300) {
        float bv0 = bi[c0], bv1 = bi[c1];
        float* g0 = gi + (size_t)row0 * G_ + c0;
        float* g1 = gi + (size_t)row0 * G_ + c1;
        #pragma unroll
        for (int r = 0; r < 64; ++r) {
            g0[(size_t)r * G_] = acc0[r] + bv0;
            g1[(size_t)r * G_] = acc1[r] + bv1;
        }
    }
}

// ---------------- Phase 2: sequential GRU scan ----------------
// 64 blocks (one per batch), 320 threads. Thread t owns Wh columns t and t+300
// as 200 packed half2 regs (~230 VGPR total, 5 waves/block, 1 block/CU).
// 2 cols/thread halves the per-step uniform h-broadcast LDS traffic
// (250 -> 125 ds_read_b128 per step per CU) at unchanged VALU issue.
__global__ __launch_bounds__(320, 1)
void scan_kernel(const float* __restrict__ gi, const half2_t* __restrict__ whp,
                 const float* __restrict__ bhn, _Float16* __restrict__ hs,
                 float* __restrict__ hstate, int TC, int first) {
    __shared__ __align__(16) _Float16 h_h[208];   // h in f16 (read via float4 broadcast)
    __shared__ float A_lds[G_];
    __shared__ float Hn_lds[H_];
    int b = blockIdx.x;
    int tid = threadIdx.x;
    int c0 = tid < 300 ? tid : 299;
    int c1 = c0 + 300;

    half2_t wa[100], wb[100];   // 200 VGPRs of packed f16 weights
    #pragma unroll
    for (int k = 0; k < 100; ++k) {
        wa[k] = whp[k * G_ + c0];   // coalesced
        wb[k] = whp[k * G_ + c1];
    }
    float bhn_r = (c1 >= 2*H_) ? bhn[c1 - 2*H_] : 0.f;

    float hj = 0.f;
    if (tid < H_) {
        hj = first ? 0.f : hstate[b * H_ + tid];
        h_h[tid] = (_Float16)hj;
    }
    if (tid >= H_ && tid < 208) h_h[tid] = (_Float16)0.f;
    __syncthreads();

    const float* girow = gi + (size_t)b * TC * G_;
    _Float16* hsb = hs + (size_t)b * TC * H_;

    float g0 = girow[c0];                        // prefetch step 0
    float g1 = girow[c1];
    for (int tc = 0; tc < TC; ++tc) {
        float g0n = 0.f, g1n = 0.f;              // prefetch next step
        if (tc + 1 < TC) {
            g0n = girow[(size_t)(tc + 1) * G_ + c0];
            g1n = girow[(size_t)(tc + 1) * G_ + c1];
        }
        // hh[c] = dot(h, Wh[:,c]) for c in {c0, c1} — h broadcast from LDS
        // as f16 float4, weights in regs; 8 fdot2 per ds_read_b128.
        float a0 = 0.f, a1 = 0.f, a2 = 0.f, a3 = 0.f;
        float b0 = 0.f, b1 = 0.f, b2 = 0.f, b3 = 0.f;
        const float4* h4 = (const float4*)h_h;
        #pragma unroll
        for (int q = 0; q < 25; ++q) {
            float4 hv = h4[q];                   // 8 halves = 4 half2
            half2_t* hp = (half2_t*)&hv;
            a0 = fdot2_(hp[0], wa[4*q+0], a0);
            a1 = fdot2_(hp[1], wa[4*q+1], a1);
            a2 = fdot2_(hp[2], wa[4*q+2], a2);
            a3 = fdot2_(hp[3], wa[4*q+3], a3);
            b0 = fdot2_(hp[0], wb[4*q+0], b0);
            b1 = fdot2_(hp[1], wb[4*q+1], b1);
            b2 = fdot2_(hp[2], wb[4*q+2], b2);
            b3 = fdot2_(hp[3], wb[4*q+3], b3);
        }
        float accA = (a0 + a1) + (a2 + a3);
        float accB = (b0 + b1) + (b2 + b3);
        if (tid < 300) {
            A_lds[c0] = g0 + accA;               // c0 in [0,300): r or z cols
            if (c1 < 2*H_) {
                A_lds[c1] = g1 + accB;           // z cols 300..399
            } else {
                A_lds[c1] = g1;                  // n cols 400..599
                Hn_lds[c1 - 2*H_] = accB + bhn_r;
            }
        }
        __syncthreads();
        if (tid < H_) {
            float r = sigmoidf_(A_lds[tid]);
            float z = sigmoidf_(A_lds[H_ + tid]);
            float n = tanh_fast_(A_lds[2*H_ + tid] + r * Hn_lds[tid]);
            hj = n + z * (hj - n);
            h_h[tid] = (_Float16)hj;
            hsb[(size_t)tc * H_ + tid] = (_Float16)hj;   // fire-and-forget store
        }
        __syncthreads();
        g0 = g0n; g1 = g1n;
    }
    if (tid < H_) hstate[b * H_ + tid] = hj;
}

// ---------------- Phase 3: out = hs @ Wo + bo ----------------
__global__ __launch_bounds__(256, 4)
void outproj_kernel(const _Float16* __restrict__ hs, const float* __restrict__ Wo,
                    const float* __restrict__ bo, float* __restrict__ out,
                    int t0, int TC) {
    int r = blockIdx.x * 256 + threadIdx.x;
    if (r >= B_ * TC) return;
    int b = r / TC, tc = r - b * TC;
    const float4* h4 = (const float4*)(hs + (size_t)r * H_);
    float acc = 0.f;
    #pragma unroll
    for (int q = 0; q < 25; ++q) {
        float4 v = h4[q];
        const _Float16* hp = (const _Float16*)&v;
        #pragma unroll
        for (int j = 0; j < 8; ++j)
            acc = fmaf((float)hp[j], Wo[q * 8 + j], acc);
    }
    out[(size_t)b * T_ + t0 + tc] = acc + bo[0];
}

extern "C" void kernel_launch(void* const* d_in, const int* in_sizes, int n_in,
                              void* d_out, int out_size, void* d_ws, size_t ws_size,
                              hipStream_t stream) {
    const float* x   = (const float*)d_in[0];
    const float* Wi  = (const float*)d_in[1];
    const float* bi  = (const float*)d_in[2];
    const float* Wh  = (const float*)d_in[3];
    const float* bhn = (const float*)d_in[4];
    const float* Wo  = (const float*)d_in[5];
    const float* bo  = (const float*)d_in[6];
    float* out = (float*)d_out;

    const size_t hstate_b = (size_t)B_ * H_ * sizeof(float);
    const size_t whp_b    = (size_t)100 * G_ * sizeof(half2_t);
    // ws layout: [gi: B*TC*G*4][hs: B*TC*H*2][hstate][whp]
    int TC = T_;
    while (TC > 64 &&
           (size_t)B_ * TC * (G_ * 4 + H_ * 2) + hstate_b + whp_b > ws_size)
        TC >>= 1;
    char* p = (char*)d_ws;
    float*    gi     = (float*)p;            p += (size_t)B_ * TC * G_ * sizeof(float);
    _Float16* hsbuf  = (_Float16*)p;         p += (size_t)B_ * TC * H_ * sizeof(_Float16);
    float*    hstate = (float*)p;            p += hstate_b;
    half2_t*  whp    = (half2_t*)p;

    prep_whp<<<dim3((100 * G_ + 255) / 256), dim3(256), 0, stream>>>(Wh, whp);

    int nchunks = T_ / TC;
    for (int c = 0; c < nchunks; ++c) {
        int t0 = c * TC;
        gi_kernel<<<dim3(B_ * TC / 64), dim3(320), 0, stream>>>(x, Wi, bi, gi, t0, TC);
        scan_kernel<<<dim3(B_), dim3(320), 0, stream>>>(gi, whp, bhn, hsbuf,
                                                        hstate, TC, c == 0);
        outproj_kernel<<<dim3((B_ * TC + 255) / 256), dim3(256), 0, stream>>>(
            hsbuf, Wo, bo, out, t0, TC);
    }
}

// Round 2
// 5515.841 us; speedup vs baseline: 1.3692x; 1.3692x over previous
//
#include <hip/hip_runtime.h>
#include <cstdint>

#define B_  64
#define T_  4096
#define F_  100
#define H_  200
#define G_  600   // 3H

typedef _Float16 half2_t __attribute__((ext_vector_type(2)));

__device__ __forceinline__ float sigmoidf_(float x) {
    return 1.0f / (1.0f + __expf(-x));
}
__device__ __forceinline__ float tanh_fast_(float x) {
    float e = __expf(-2.0f * x);
    return (1.0f - e) / (1.0f + e);
}

__device__ __forceinline__ float fdot2_(half2_t a, half2_t b, float c) {
#if __has_builtin(__builtin_amdgcn_fdot2)
    return __builtin_amdgcn_fdot2(a, b, c, false);
#else
    return fmaf((float)a.x, (float)b.x, fmaf((float)a.y, (float)b.y, c));
#endif
}

// lane-pair (xor 1) sum via DPP quad_perm [1,0,3,2] — pure VALU, no LDS pipe.
__device__ __forceinline__ float dpp_xor1_add(float x) {
    int xi = __float_as_int(x);
    int yi = __builtin_amdgcn_update_dpp(0, xi, 0xB1, 0xF, 0xF, true);
    return x + __int_as_float(yi);
}

// ---------------- Phase 0: pack Wh (f32, row-major [200,600]) -> half2 [104][600] ----------------
// whp[k*600 + c] = (Wh[2k][c], Wh[2k+1][c]); rows 100..103 zero-padded (K padded 200->208)
__global__ void prep_whp(const float* __restrict__ Wh, half2_t* __restrict__ whp) {
    int i = blockIdx.x * 256 + threadIdx.x;
    if (i < 104 * G_) {
        int k = i / G_, c = i - k * G_;
        half2_t v;
        v.x = (k < 100) ? (_Float16)Wh[(2 * k) * G_ + c] : (_Float16)0.f;
        v.y = (k < 100) ? (_Float16)Wh[(2 * k + 1) * G_ + c] : (_Float16)0.f;
        whp[i] = v;
    }
}

// ---------------- Phase 1: gi = x @ Wi + bi (fp32) ----------------
// (session-verified 640-thread version: 1 col/thread, no register-pressure cliff)
__global__ __launch_bounds__(640, 1)
void gi_kernel(const float* __restrict__ x, const float* __restrict__ Wi,
               const float* __restrict__ bi, float* __restrict__ gi,
               int t0, int TC) {
    __shared__ float xT[F_ * 68];
    int row0 = blockIdx.x * 64;
    int b    = row0 / TC;
    int tc0  = row0 - b * TC;
    const float* xrow = x + ((size_t)b * T_ + t0 + tc0) * F_;
    for (int i = threadIdx.x; i < 64 * F_; i += 640) {
        int r = i / F_, f = i - r * F_;
        xT[f * 68 + r] = xrow[i];
    }
    __syncthreads();
    int col = threadIdx.x < G_ ? threadIdx.x : G_ - 1;
    float acc[64];
    #pragma unroll
    for (int r = 0; r < 64; ++r) acc[r] = 0.f;
    for (int f = 0; f < F_; ++f) {
        float wi = Wi[f * G_ + col];
        const float4* xf = (const float4*)&xT[f * 68];
        #pragma unroll
        for (int q = 0; q < 16; ++q) {
            float4 v = xf[q];
            acc[4*q+0] = fmaf(v.x, wi, acc[4*q+0]);
            acc[4*q+1] = fmaf(v.y, wi, acc[4*q+1]);
            acc[4*q+2] = fmaf(v.z, wi, acc[4*q+2]);
            acc[4*q+3] = fmaf(v.w, wi, acc[4*q+3]);
        }
    }
    if (threadIdx.x < G_) {
        float bv = bi[col];
        float* grow = gi + (size_t)row0 * G_ + col;
        #pragma unroll 4
        for (int r = 0; r < 64; ++r) grow[(size_t)r * G_] = acc[r] + bv;
    }
}

// ---------------- Phase 2: sequential GRU scan ----------------
// 64 blocks (one per batch), 640 threads (10 waves). Lane pair (2p, 2p+1) owns
// columns {p, p+300}; lane s=tid&1 covers K-elements [104s, 104s+104).
// Weights: 2 cols x 52 half2 = 104 VGPRs (stays under the ~128-VGPR allocator
// cliff that pushed round-1's 200-reg version into AGPR/scratch traffic).
// LDS broadcast per step: 13 ds_read_b128/thread x 10 waves = 130 wave-instrs
// (vs 250 in the 5152us baseline) — each 16B h-chunk is reused for 2 columns.
// Lane-pair partials combine via DPP quad_perm add (VALU, not LDS pipe).
__global__ __launch_bounds__(640, 1)
void scan_kernel(const float* __restrict__ gi, const half2_t* __restrict__ whp,
                 const float* __restrict__ bhn, _Float16* __restrict__ hs,
                 float* __restrict__ hstate, int TC, int first) {
    __shared__ __align__(16) _Float16 h_h[208];   // h in f16, padded 200->208 with zeros
    __shared__ float A_lds[G_];
    __shared__ float Hn_lds[H_];
    int b = blockIdx.x;
    int tid = threadIdx.x;
    int p = tid >> 1;                 // pair id, [0,320)
    int s = tid & 1;                  // K-half
    if (p >= 300) p = 299;            // clamp: threads 600..639 compute duplicates, never write
    int c0 = p;
    int c1 = p + 300;

    half2_t wa[52], wb[52];           // 104 VGPRs of packed f16 weights
    #pragma unroll
    for (int j = 0; j < 52; ++j) {
        wa[j] = whp[(52 * s + j) * G_ + c0];
        wb[j] = whp[(52 * s + j) * G_ + c1];
    }
    float bhn_r = (c1 >= 2*H_) ? bhn[c1 - 2*H_] : 0.f;

    float hj = 0.f;
    if (tid < H_) {
        hj = first ? 0.f : hstate[b * H_ + tid];
        h_h[tid] = (_Float16)hj;
    }
    if (tid >= H_ && tid < 208) h_h[tid] = (_Float16)0.f;
    __syncthreads();

    const float* girow = gi + (size_t)b * TC * G_;
    _Float16* hsb = hs + (size_t)b * TC * H_;

    float g0 = 0.f, g1 = 0.f;
    if (s == 0) { g0 = girow[c0]; g1 = girow[c1]; }       // prefetch step 0
    for (int tc = 0; tc < TC; ++tc) {
        float g0n = 0.f, g1n = 0.f;                       // prefetch next step
        if (s == 0 && tc + 1 < TC) {
            g0n = girow[(size_t)(tc + 1) * G_ + c0];
            g1n = girow[(size_t)(tc + 1) * G_ + c1];
        }
        // partial dots over this lane's K-half; h broadcast from LDS as f16 float4
        float a0 = 0.f, a1 = 0.f, a2 = 0.f, a3 = 0.f;
        float b0 = 0.f, b1 = 0.f, b2 = 0.f, b3 = 0.f;
        const float4* h4 = (const float4*)(h_h + 104 * s);   // byte offset 208*s, 16B-aligned
        #pragma unroll
        for (int q = 0; q < 13; ++q) {
            float4 hv = h4[q];                   // 8 halves = 4 half2
            half2_t* hp = (half2_t*)&hv;
            a0 = fdot2_(hp[0], wa[4*q+0], a0);
            a1 = fdot2_(hp[1], wa[4*q+1], a1);
            a2 = fdot2_(hp[2], wa[4*q+2], a2);
            a3 = fdot2_(hp[3], wa[4*q+3], a3);
            b0 = fdot2_(hp[0], wb[4*q+0], b0);
            b1 = fdot2_(hp[1], wb[4*q+1], b1);
            b2 = fdot2_(hp[2], wb[4*q+2], b2);
            b3 = fdot2_(hp[3], wb[4*q+3], b3);
        }
        float accA = dpp_xor1_add((a0 + a1) + (a2 + a3));   // sum across lane pair
        float accB = dpp_xor1_add((b0 + b1) + (b2 + b3));
        if (s == 0 && c0 < 300) {
            A_lds[c0] = g0 + accA;               // c0 in [0,300): r or z cols
            if (c1 < 2*H_) {
                A_lds[c1] = g1 + accB;           // z cols 300..399
            } else {
                A_lds[c1] = g1;                  // n cols 400..599
                Hn_lds[c1 - 2*H_] = accB + bhn_r;
            }
        }
        __syncthreads();
        if (tid < H_) {
            float r = sigmoidf_(A_lds[tid]);
            float z = sigmoidf_(A_lds[H_ + tid]);
            float n = tanh_fast_(A_lds[2*H_ + tid] + r * Hn_lds[tid]);
            hj = n + z * (hj - n);
            h_h[tid] = (_Float16)hj;
            hsb[(size_t)tc * H_ + tid] = (_Float16)hj;   // fire-and-forget store
        }
        __syncthreads();
        g0 = g0n; g1 = g1n;
    }
    if (tid < H_) hstate[b * H_ + tid] = hj;
}

// ---------------- Phase 3: out = hs @ Wo + bo ----------------
__global__ __launch_bounds__(256, 4)
void outproj_kernel(const _Float16* __restrict__ hs, const float* __restrict__ Wo,
                    const float* __restrict__ bo, float* __restrict__ out,
                    int t0, int TC) {
    int r = blockIdx.x * 256 + threadIdx.x;
    if (r >= B_ * TC) return;
    int b = r / TC, tc = r - b * TC;
    const float4* h4 = (const float4*)(hs + (size_t)r * H_);
    float acc = 0.f;
    #pragma unroll
    for (int q = 0; q < 25; ++q) {
        float4 v = h4[q];
        const _Float16* hp = (const _Float16*)&v;
        #pragma unroll
        for (int j = 0; j < 8; ++j)
            acc = fmaf((float)hp[j], Wo[q * 8 + j], acc);
    }
    out[(size_t)b * T_ + t0 + tc] = acc + bo[0];
}

extern "C" void kernel_launch(void* const* d_in, const int* in_sizes, int n_in,
                              void* d_out, int out_size, void* d_ws, size_t ws_size,
                              hipStream_t stream) {
    const float* x   = (const float*)d_in[0];
    const float* Wi  = (const float*)d_in[1];
    const float* bi  = (const float*)d_in[2];
    const float* Wh  = (const float*)d_in[3];
    const float* bhn = (const float*)d_in[4];
    const float* Wo  = (const float*)d_in[5];
    const float* bo  = (const float*)d_in[6];
    float* out = (float*)d_out;

    const size_t hstate_b = (size_t)B_ * H_ * sizeof(float);
    const size_t whp_b    = (size_t)104 * G_ * sizeof(half2_t);
    // ws layout: [gi: B*TC*G*4][hs: B*TC*H*2][hstate][whp]
    int TC = T_;
    while (TC > 64 &&
           (size_t)B_ * TC * (G_ * 4 + H_ * 2) + hstate_b + whp_b > ws_size)
        TC >>= 1;
    char* p = (char*)d_ws;
    float*    gi     = (float*)p;            p += (size_t)B_ * TC * G_ * sizeof(float);
    _Float16* hsbuf  = (_Float16*)p;         p += (size_t)B_ * TC * H_ * sizeof(_Float16);
    float*    hstate = (float*)p;            p += hstate_b;
    half2_t*  whp    = (half2_t*)p;

    prep_whp<<<dim3((104 * G_ + 255) / 256), dim3(256), 0, stream>>>(Wh, whp);

    int nchunks = T_ / TC;
    for (int c = 0; c < nchunks; ++c) {
        int t0 = c * TC;
        gi_kernel<<<dim3(B_ * TC / 64), dim3(640), 0, stream>>>(x, Wi, bi, gi, t0, TC);
        scan_kernel<<<dim3(B_), dim3(640), 0, stream>>>(gi, whp, bhn, hsbuf,
                                                        hstate, TC, c == 0);
        outproj_kernel<<<dim3((B_ * TC + 255) / 256), dim3(256), 0, stream>>>(
            hsbuf, Wo, bo, out, t0, TC);
    }
}